// Round 3
// baseline (32653.540 us; speedup 1.0000x reference)
//
#include <hip/hip_runtime.h>
#include <hip/hip_bf16.h>

#define NB 4096
#define MDIM 327
#define NDIM 800
#define NLAYERS 9
#define NPIX 800
#define CHN 32
#define NBP (NB * NPIX)

typedef __hip_bfloat16 bf16;

// ---------------- setup ----------------

__global__ void k_copy(const float* __restrict__ src, float* __restrict__ dst,
                       long long n) {
    long long i0 = (long long)blockIdx.x * 256 + threadIdx.x;
    long long stride = (long long)gridDim.x * 256;
    for (long long i = i0; i < n; i += stride) dst[i] = src[i];
}

// transpose [O=32][I*9=288] -> [288][32]
__global__ void k_wtrans(const float* __restrict__ src, float* __restrict__ dst) {
    int idx = blockIdx.x * 256 + threadIdx.x;
    if (idx >= 9216) return;
    int o = idx / 288, r = idx % 288;
    dst[r * 32 + o] = src[idx];
}

__global__ void k_phitphi(const float* __restrict__ W, float* __restrict__ P) {
    int b = blockIdx.x * 16 + threadIdx.x;
    int a = blockIdx.y * 16 + threadIdx.y;
    float acc = 0.f;
    for (int k = 0; k < MDIM; ++k)
        acc += W[k * NDIM + a] * W[k * NDIM + b];
    P[(size_t)a * NDIM + b] = acc;
}

__global__ void k_wloss(const float* __restrict__ W, float* __restrict__ out) {
    int idx = blockIdx.x * 256 + threadIdx.x;
    if (idx >= MDIM * MDIM) return;
    int a = idx / MDIM, b = idx % MDIM;
    float acc = 0.f;
    for (int n = 0; n < NDIM; ++n)
        acc += W[a * NDIM + n] * W[b * NDIM + n];
    if (a == b) acc -= 1.f;
    out[idx] = acc;
}

__global__ void k_phitb(const float* __restrict__ y, const float* __restrict__ W,
                        float* __restrict__ PB) {
    int idx = blockIdx.x * 256 + threadIdx.x;
    if (idx >= NBP) return;
    int b = idx / NDIM, n = idx % NDIM;
    float acc = 0.f;
    for (int k = 0; k < MDIM; ++k)
        acc += y[b * MDIM + k] * W[k * NDIM + n];
    PB[idx] = acc;
}

// ---------------- X update ----------------

__global__ void k_x0(const float* __restrict__ PB, float* __restrict__ X1,
                     const float* __restrict__ hv) {
    int idx = blockIdx.x * 256 + threadIdx.x;
    if (idx >= NBP) return;
    X1[idx] = hv[0] * PB[idx];
}

// H = hatx = (1+tx)*Xc - tx*Xp
__global__ void k_hatx(const float* __restrict__ Xc, const float* __restrict__ Xp,
                       float* __restrict__ H, const float* __restrict__ txv,
                       int layer, int mode) {
    int idx = blockIdx.x * 256 + threadIdx.x;
    if (idx >= NBP) return;
    float tx = txv[layer];
    float xc = Xc[idx];
    float xp = (mode >= 2) ? Xp[idx] : 0.f;
    H[idx] = (1.f + tx) * xc - tx * xp;
}

// Xn = H*(1-h*b1) + h*PB - h*(H@P) + h*b1*Z - h*L
__global__ void k_xmm(const float* __restrict__ H, const float* __restrict__ P,
                      const float* __restrict__ PB, const float* __restrict__ Lc,
                      const float* __restrict__ Zc, float* __restrict__ Xn,
                      const float* __restrict__ hv, const float* __restrict__ b1v,
                      int layer, int mode) {
    __shared__ float As[64][17];
    __shared__ float Bs[16][65];
    int tid = threadIdx.x;
    float h = hv[layer], b1 = b1v[layer];
    int rowbase = blockIdx.y * 64, colbase = blockIdx.x * 64;
    int ttx = tid % 16, tty = tid / 16;
    float acc[4][4];
#pragma unroll
    for (int r = 0; r < 4; ++r)
#pragma unroll
        for (int c = 0; c < 4; ++c) acc[r][c] = 0.f;

    int am = tid >> 2, ak4 = (tid & 3) * 4;
    int bk = tid >> 4, bn4 = (tid & 15) * 4;

    for (int kt = 0; kt < 50; ++kt) {
        int k0 = kt * 16;
        {
            const float* hp = H + (size_t)(rowbase + am) * NDIM + k0 + ak4;
#pragma unroll
            for (int j = 0; j < 4; ++j) As[am][ak4 + j] = hp[j];
        }
        {
            const float* pr = P + (size_t)(k0 + bk) * NDIM + colbase + bn4;
#pragma unroll
            for (int j = 0; j < 4; ++j) {
                int col = colbase + bn4 + j;
                Bs[bk][bn4 + j] = (col < NDIM) ? pr[j] : 0.f;
            }
        }
        __syncthreads();
#pragma unroll
        for (int kk = 0; kk < 16; ++kk) {
            float a[4], b[4];
#pragma unroll
            for (int r = 0; r < 4; ++r) a[r] = As[tty * 4 + r][kk];
#pragma unroll
            for (int c = 0; c < 4; ++c) b[c] = Bs[kk][ttx * 4 + c];
#pragma unroll
            for (int r = 0; r < 4; ++r)
#pragma unroll
                for (int c = 0; c < 4; ++c) acc[r][c] += a[r] * b[c];
        }
        __syncthreads();
    }

#pragma unroll
    for (int r = 0; r < 4; ++r) {
        int row = rowbase + tty * 4 + r;
#pragma unroll
        for (int c = 0; c < 4; ++c) {
            int col = colbase + ttx * 4 + c;
            if (col >= NDIM) continue;
            size_t idx = (size_t)row * NDIM + col;
            float hx = H[idx];
            float zt = (mode == 2) ? Zc[idx] : 0.f;
            float lt = (mode == 2) ? Lc[idx] : 0.f;
            Xn[idx] = hx * (1.f - h * b1) + h * PB[idx] - h * acc[r][c] + h * b1 * zt - h * lt;
        }
    }
}

// ---------------- z_flat ----------------

__global__ void k_zflat(const float* __restrict__ Xn, const float* __restrict__ Zc,
                        const float* __restrict__ Zp, const float* __restrict__ Lc,
                        float* __restrict__ zf,
                        const float* __restrict__ hv, const float* __restrict__ b2v,
                        const float* __restrict__ tzv, int layer, int mode) {
    int idx = blockIdx.x * 256 + threadIdx.x;
    if (idx >= NBP) return;
    float h = hv[layer], b2 = b2v[layer], tz = tzv[layer];
    float hatz, lt;
    if (mode == 0) { hatz = 0.f; lt = 0.f; }
    else if (mode == 1) { hatz = (1.f + tz) * Zc[idx]; lt = 0.f; }
    else {
        float zc = Zc[idx], zp = Zp[idx];
        hatz = zc + tz * (zc - zp);
        lt = Lc[idx];
    }
    zf[idx] = hatz + h * (lt + b2 * (Xn[idx] - hatz));
}

// ---------------- convs (f32) ----------------
// conv32/conv2b v3: 256 threads = 4 waves.
// LDS tile: 16 ch x 12 rows x 44 words (stride 44, px x at word x+1,
// words 0,41..43 zero). Staging: one thread per row (tid<192): 10 aligned
// float4 global loads, register repack, 11 aligned ds_write_b128 (quad
// stride 11 is coprime with 8 -> writes spread across bank-quads).
// Compute lane map: lane<50, ry=lane/5, xg=(lane%5)*8; each lane owns
// 8 och x 8 px (conv32). Per ci: 9 ds_read_b128 feed 576 FMAs.
// Accumulation order per output stays ci(0..31) -> ky -> kx.

__device__ __forceinline__ float4 soft4(float4 u, float thr) {
    float a;
    a = fabsf(u.x) - thr; u.x = (a > 0.f) ? copysignf(a, u.x) : 0.f;
    a = fabsf(u.y) - thr; u.y = (a > 0.f) ? copysignf(a, u.y) : 0.f;
    a = fabsf(u.z) - thr; u.z = (a > 0.f) ? copysignf(a, u.z) : 0.f;
    a = fabsf(u.w) - thr; u.w = (a > 0.f) ? copysignf(a, u.w) : 0.f;
    return u;
}

// stage one padded row (44 words) from global; gr<0/>=20 -> zero row
__device__ __forceinline__ void stage_row(const float* __restrict__ gsrc,
                                          float* __restrict__ ldsrow,
                                          int gr, int softflag, float thr) {
    float4* drow = reinterpret_cast<float4*>(ldsrow);
    if (gr >= 0 && gr < 20) {
        const float4* src = reinterpret_cast<const float4*>(gsrc);
        float4 a0 = src[0], a1 = src[1], a2 = src[2], a3 = src[3], a4 = src[4];
        if (softflag) {
            a0 = soft4(a0, thr); a1 = soft4(a1, thr); a2 = soft4(a2, thr);
            a3 = soft4(a3, thr); a4 = soft4(a4, thr);
        }
        drow[0] = make_float4(0.f,  a0.x, a0.y, a0.z);
        drow[1] = make_float4(a0.w, a1.x, a1.y, a1.z);
        drow[2] = make_float4(a1.w, a2.x, a2.y, a2.z);
        drow[3] = make_float4(a2.w, a3.x, a3.y, a3.z);
        drow[4] = make_float4(a3.w, a4.x, a4.y, a4.z);
        float carry = a4.w;
        a0 = src[5]; a1 = src[6]; a2 = src[7]; a3 = src[8]; a4 = src[9];
        if (softflag) {
            a0 = soft4(a0, thr); a1 = soft4(a1, thr); a2 = soft4(a2, thr);
            a3 = soft4(a3, thr); a4 = soft4(a4, thr);
        }
        drow[5] = make_float4(carry, a0.x, a0.y, a0.z);
        drow[6] = make_float4(a0.w,  a1.x, a1.y, a1.z);
        drow[7] = make_float4(a1.w,  a2.x, a2.y, a2.z);
        drow[8] = make_float4(a2.w,  a3.x, a3.y, a3.z);
        drow[9] = make_float4(a3.w,  a4.x, a4.y, a4.z);
        drow[10] = make_float4(a4.w, 0.f, 0.f, 0.f);
    } else {
        float4 z = make_float4(0.f, 0.f, 0.f, 0.f);
#pragma unroll
        for (int q = 0; q < 11; ++q) drow[q] = z;
    }
}

// 1->32 conv + relu. w: [32][1][3][3] raw. (cheap; unchanged structure)
__global__ void __launch_bounds__(512, 4)
k_conv1f(const float* __restrict__ zf, float* __restrict__ out,
         const float* __restrict__ w, int c0) {
    __shared__ float zs[22 * 42];
    int tid = threadIdx.x;
    int img = c0 + blockIdx.x;
    for (int i = tid; i < 22 * 42; i += 512) zs[i] = 0.f;
    __syncthreads();
    for (int p = tid; p < NPIX; p += 512) {
        int y = p / 40, x = p % 40;
        zs[(y + 1) * 42 + (x + 1)] = zf[(size_t)img * NPIX + p];
    }
    __syncthreads();

    int wv = __builtin_amdgcn_readfirstlane(tid >> 6);
    int ob = wv * 4;
    int lane = tid & 63;
    int ry = lane / 5;
    int xg = (lane % 5) * 8;
    bool active = lane < 50;

    float wreg[4][9];
#pragma unroll
    for (int oo = 0; oo < 4; ++oo)
#pragma unroll
        for (int q = 0; q < 9; ++q) wreg[oo][q] = w[(ob + oo) * 9 + q];

    if (active) {
#pragma unroll
        for (int half = 0; half < 2; ++half) {
            int orow = half * 10 + ry;
            float pv[3][10];
#pragma unroll
            for (int r = 0; r < 3; ++r)
#pragma unroll
                for (int j = 0; j < 10; ++j)
                    pv[r][j] = zs[(orow + r) * 42 + xg + j];
            float acc[4][8];
#pragma unroll
            for (int oo = 0; oo < 4; ++oo)
#pragma unroll
                for (int j = 0; j < 8; ++j) acc[oo][j] = 0.f;
#pragma unroll
            for (int ky = 0; ky < 3; ++ky)
#pragma unroll
                for (int kx = 0; kx < 3; ++kx) {
                    int q = ky * 3 + kx;
#pragma unroll
                    for (int j = 0; j < 8; ++j) {
                        float p = pv[ky][kx + j];
                        acc[0][j] += wreg[0][q] * p;
                        acc[1][j] += wreg[1][q] * p;
                        acc[2][j] += wreg[2][q] * p;
                        acc[3][j] += wreg[3][q] * p;
                    }
                }
#pragma unroll
            for (int oo = 0; oo < 4; ++oo) {
                float* op = out + (size_t)blockIdx.x * 25600 + (ob + oo) * 800
                            + orow * 40 + xg;
#pragma unroll
                for (int j = 0; j < 8; ++j) op[j] = fmaxf(acc[oo][j], 0.f);
            }
        }
    }
}

// 32->32 conv. wT: [ci*9+ky*3+kx][32 o]. Optional soft-threshold on input,
// relu on output. 4 waves x 8 och.
__global__ void __launch_bounds__(256, 4)
k_conv32(const float* __restrict__ in, float* __restrict__ out,
         const float* __restrict__ wT, const float* __restrict__ thrv,
         int layer, int softflag, int reluflag) {
    __shared__ alignas(16) float inS[16 * 12 * 44];   // 33792 B
    int tid = threadIdx.x;
    const float* ip = in + (size_t)blockIdx.x * 25600;
    float thr = softflag ? fabsf(thrv[layer]) : 0.f;

    int wv = __builtin_amdgcn_readfirstlane(tid >> 6);   // 0..3
    int ob = wv * 8;
    int lane = tid & 63;
    int ry = lane / 5;
    int xg = (lane % 5) * 8;
    bool active = lane < 50;

    int sc = tid / 12, srr = tid - (tid / 12) * 12;   // staging row (tid<192)

    for (int half = 0; half < 2; ++half) {
        float acc[8][8];
#pragma unroll
        for (int oo = 0; oo < 8; ++oo)
#pragma unroll
            for (int j = 0; j < 8; ++j) acc[oo][j] = 0.f;

        for (int cg = 0; cg < 2; ++cg) {
            __syncthreads();   // prior compute done reading inS
            if (tid < 192) {
                int gr = half * 10 - 1 + srr;
                stage_row(ip + (size_t)(cg * 16 + sc) * 800 + gr * 40,
                          inS + sc * 528 + srr * 44, gr, softflag, thr);
            }
            __syncthreads();   // staged data visible

            if (active) {
#pragma unroll 1
                for (int ci = 0; ci < 16; ++ci) {
                    const float* rs = inS + ci * 528 + ry * 44 + xg;
                    const float* wc = wT + (size_t)(cg * 16 + ci) * 288 + ob;
#pragma unroll
                    for (int ky = 0; ky < 3; ++ky) {
                        const float4* rp =
                            reinterpret_cast<const float4*>(rs + ky * 44);
                        float4 u = rp[0], v2 = rp[1], w2 = rp[2];
                        float p[12];
                        p[0] = u.x;  p[1] = u.y;  p[2] = u.z;  p[3] = u.w;
                        p[4] = v2.x; p[5] = v2.y; p[6] = v2.z; p[7] = v2.w;
                        p[8] = w2.x; p[9] = w2.y; p[10] = w2.z; p[11] = w2.w;
#pragma unroll
                        for (int kx = 0; kx < 3; ++kx) {
                            int q = ky * 3 + kx;
#pragma unroll
                            for (int oo = 0; oo < 8; ++oo) {
                                float wq = wc[q * 32 + oo];
#pragma unroll
                                for (int j = 0; j < 8; ++j)
                                    acc[oo][j] += wq * p[kx + j];
                            }
                        }
                    }
                }
            }
        }

        if (active) {
            int orow = half * 10 + ry;
#pragma unroll
            for (int oo = 0; oo < 8; ++oo) {
                float* op = out + (size_t)blockIdx.x * 25600 + (ob + oo) * 800
                            + orow * 40 + xg;
                float4 lo, hi;
                lo.x = acc[oo][0]; lo.y = acc[oo][1];
                lo.z = acc[oo][2]; lo.w = acc[oo][3];
                hi.x = acc[oo][4]; hi.y = acc[oo][5];
                hi.z = acc[oo][6]; hi.w = acc[oo][7];
                if (reluflag) {
                    lo.x = fmaxf(lo.x, 0.f); lo.y = fmaxf(lo.y, 0.f);
                    lo.z = fmaxf(lo.z, 0.f); lo.w = fmaxf(lo.w, 0.f);
                    hi.x = fmaxf(hi.x, 0.f); hi.y = fmaxf(hi.y, 0.f);
                    hi.z = fmaxf(hi.z, 0.f); hi.w = fmaxf(hi.w, 0.f);
                }
                reinterpret_cast<float4*>(op)[0] = lo;
                reinterpret_cast<float4*>(op)[1] = hi;
            }
        }
    }
}

// 32->1 conv; writes f32 to global output; optional -z_in.
// 4 waves; wave wv owns local channels wv*4..wv*4+3 of each 16-ch group;
// partial sums reduced through LDS (aliased on inS).
__global__ void __launch_bounds__(256, 4)
k_conv2b(const float* __restrict__ in, const float* __restrict__ w,
         const float* __restrict__ zf, float* __restrict__ out,
         int subz, int c0) {
    __shared__ alignas(16) float inS[16 * 12 * 44];   // head reused as psum
    float* psum = inS;
    int tid = threadIdx.x;
    int img = c0 + blockIdx.x;
    const float* ip = in + (size_t)blockIdx.x * 25600;

    int wv = __builtin_amdgcn_readfirstlane(tid >> 6);
    int lane = tid & 63;
    int ry = lane / 5;
    int xg = (lane % 5) * 8;
    bool active = lane < 50;

    int sc = tid / 12, srr = tid - (tid / 12) * 12;

    for (int half = 0; half < 2; ++half) {
        float acc[8];
#pragma unroll
        for (int j = 0; j < 8; ++j) acc[j] = 0.f;

        for (int cg = 0; cg < 2; ++cg) {
            __syncthreads();   // prior reads of inS (compute/reduce) done
            if (tid < 192) {
                int gr = half * 10 - 1 + srr;
                stage_row(ip + (size_t)(cg * 16 + sc) * 800 + gr * 40,
                          inS + sc * 528 + srr * 44, gr, 0, 0.f);
            }
            __syncthreads();

            if (active) {
#pragma unroll
                for (int k = 0; k < 4; ++k) {
                    int cil = wv * 4 + k;   // 0..15
                    const float* rs = inS + cil * 528 + ry * 44 + xg;
                    const float* wc = w + (size_t)(cg * 16 + cil) * 9;
#pragma unroll
                    for (int ky = 0; ky < 3; ++ky) {
                        const float4* rp =
                            reinterpret_cast<const float4*>(rs + ky * 44);
                        float4 u = rp[0], v2 = rp[1], w2 = rp[2];
                        float p[12];
                        p[0] = u.x;  p[1] = u.y;  p[2] = u.z;  p[3] = u.w;
                        p[4] = v2.x; p[5] = v2.y; p[6] = v2.z; p[7] = v2.w;
                        p[8] = w2.x; p[9] = w2.y; p[10] = w2.z; p[11] = w2.w;
#pragma unroll
                        for (int kx = 0; kx < 3; ++kx) {
                            float wq = wc[ky * 3 + kx];
#pragma unroll
                            for (int j = 0; j < 8; ++j)
                                acc[j] += wq * p[kx + j];
                        }
                    }
                }
            }
        }

        __syncthreads();   // all compute reads of inS done -> reuse as psum
        if (active) {
#pragma unroll
            for (int j = 0; j < 8; ++j)
                psum[wv * 400 + ry * 40 + xg + j] = acc[j];
        }
        __syncthreads();
        for (int p = tid; p < 400; p += 256) {
            float s = 0.f;
#pragma unroll
            for (int u = 0; u < 4; ++u) s += psum[u * 400 + p];
            size_t gidx = (size_t)img * NPIX + half * 400 + p;
            if (subz) s -= zf[gidx];
            out[gidx] = s;
        }
    }
}

// ---------------- L update ----------------

__global__ void k_lup(const float* __restrict__ Xn, const float* __restrict__ Zn,
                      const float* __restrict__ Lc, const float* __restrict__ Lp,
                      float* __restrict__ Ln,
                      const float* __restrict__ hv, const float* __restrict__ b1v,
                      const float* __restrict__ tLv, int layer, int mode) {
    int idx = blockIdx.x * 256 + threadIdx.x;
    if (idx >= NBP) return;
    float h = hv[layer], b1 = b1v[layer], tL = tLv[layer];
    float hatL;
    if (mode == 0) hatL = 0.f;
    else if (mode == 1) hatL = (1.f + tL) * Lc[idx];
    else {
        float lc = Lc[idx], lp = Lp[idx];
        hatL = lc + tL * (lc - lp);
    }
    Ln[idx] = hatL + h * b1 * (Xn[idx] - Zn[idx]);
}

// ---------------- host ----------------
// PROBE-VERIFIED (round 5): inputs f32, dict order, n_in=14, output f32, ws>=120MB.

extern "C" void kernel_launch(void* const* d_in, const int* in_sizes, int n_in,
                              void* d_out, int out_size, void* d_ws, size_t ws_size,
                              hipStream_t stream) {
    const float* y    = (const float*)d_in[0];
    const float* Wf   = (const float*)d_in[2];
    const float* b1v  = (const float*)d_in[3];
    const float* b2v  = (const float*)d_in[4];
    const float* hv   = (const float*)d_in[5];
    const float* stv  = (const float*)d_in[6];
    const float* txv  = (const float*)d_in[7];
    const float* tzv  = (const float*)d_in[8];
    const float* tLv  = (const float*)d_in[9];
    const float* w1f  = (const float*)d_in[10];
    const float* w2f  = (const float*)d_in[11];
    const float* w1b  = (const float*)d_in[12];
    const float* w2b  = (const float*)d_in[13];

    float* Zout  = (float*)d_out;                       // [9][NBP]
    float* Sout  = Zout + (size_t)NLAYERS * NBP;        // [9][NBP]
    float* WLout = Zout + 2 * (size_t)NLAYERS * NBP;    // [327*327]

    char* ws = (char*)d_ws;
    size_t off = 0;
    auto alloc = [&](size_t bytes) -> void* {
        void* p = ws + off;
        off += (bytes + 255) & ~(size_t)255;
        return p;
    };

    float* w2fT = (float*)alloc(9216 * 4);
    float* w1bT = (float*)alloc(9216 * 4);
    float* P    = (float*)alloc((size_t)NDIM * NDIM * 4);
    float* PB   = (float*)alloc((size_t)NBP * 4);
    float* Xa   = (float*)alloc((size_t)NBP * 4);
    float* Xb_  = (float*)alloc((size_t)NBP * 4);
    float* La   = (float*)alloc((size_t)NBP * 4);
    float* Lb_  = (float*)alloc((size_t)NBP * 4);
    float* zfb  = (float*)alloc((size_t)NBP * 4);   // doubles as hatx temp

    size_t rem = (ws_size > off + 4096) ? (ws_size - off - 4096) : 0;
    long long Ci = (long long)(rem / (2 * 25600 * 4));
    if (Ci > 2048) Ci = 2048;
    if (Ci < 1) Ci = 1;
    int C = (int)Ci;
    float* Abuf = (float*)alloc((size_t)C * 25600 * 4);
    float* Bbuf = (float*)alloc((size_t)C * 25600 * 4);

    int ew_grid = (NBP + 255) / 256;

    k_wtrans<<<36, 256, 0, stream>>>(w2f, w2fT);
    k_wtrans<<<36, 256, 0, stream>>>(w1b, w1bT);
    k_phitphi<<<dim3(50, 50), dim3(16, 16), 0, stream>>>(Wf, P);
    k_wloss<<<(MDIM * MDIM + 255) / 256, 256, 0, stream>>>(Wf, WLout);
    k_phitb<<<ew_grid, 256, 0, stream>>>(y, Wf, PB);

    float* Xcur = Xa; float* Xoth = Xb_;
    float* Lcur = La; float* Loth = Lb_;

    for (int i = 0; i < NLAYERS; ++i) {
        int mode = (i == 0) ? 0 : ((i == 1) ? 1 : 2);
        float* Zw = Zout + (size_t)i * NBP;
        const float* Zc = Zout + (size_t)((i >= 1) ? (i - 1) : 0) * NBP;
        const float* Zp = Zout + (size_t)((i >= 2) ? (i - 2) : 0) * NBP;

        float* Xn;
        if (i == 0) {
            Xn = Xcur;
            k_x0<<<ew_grid, 256, 0, stream>>>(PB, Xn, hv);
        } else {
            k_hatx<<<ew_grid, 256, 0, stream>>>(Xcur, Xoth, zfb, txv, i, mode);
            Xn = Xoth;
            k_xmm<<<dim3(13, 64), 256, 0, stream>>>(zfb, P, PB, Lcur, Zc, Xn,
                                                    hv, b1v, i, mode);
            float* t = Xcur; Xcur = Xn; Xoth = t;
        }

        k_zflat<<<ew_grid, 256, 0, stream>>>(Xn, Zc, Zp, Lcur, zfb, hv, b2v, tzv, i, mode);

        for (int c0 = 0; c0 < NB; c0 += C) {
            int g = (NB - c0 < C) ? (NB - c0) : C;
            k_conv1f<<<g, 512, 0, stream>>>(zfb, Abuf, w1f, c0);
            k_conv32<<<g, 256, 0, stream>>>(Abuf, Bbuf, w2fT, stv, i, 0, 0);   // x_fwd
            k_conv32<<<g, 256, 0, stream>>>(Bbuf, Abuf, w1bT, stv, i, 1, 1);   // relu(c1b(soft(x_fwd)))
            k_conv2b<<<g, 256, 0, stream>>>(Abuf, w2b, zfb, Zw, 0, c0);        // Zs[i]
            k_conv32<<<g, 256, 0, stream>>>(Bbuf, Abuf, w1bT, stv, i, 0, 1);   // relu(c1b(x_fwd))
            k_conv2b<<<g, 256, 0, stream>>>(Abuf, w2b, zfb, Sout + (size_t)i * NBP, 1, c0); // syms[i]
        }

        k_lup<<<ew_grid, 256, 0, stream>>>(Xn, Zw, Lcur, Loth, Loth, hv, b1v, tLv, i, mode);
        { float* t = Lcur; Lcur = Loth; Loth = t; }
    }
}

// Round 4
// 25687.918 us; speedup vs baseline: 1.2712x; 1.2712x over previous
//
#include <hip/hip_runtime.h>
#include <hip/hip_bf16.h>

#define NB 4096
#define MDIM 327
#define NDIM 800
#define NLAYERS 9
#define NPIX 800
#define CHN 32
#define NBP (NB * NPIX)

typedef __hip_bfloat16 bf16;

// Permuted lane -> (ry, xgroup) map, encoded (ry<<4)|g.
// Built so each consecutive 8-lane phase covers all 8 LDS bank-quads
// exactly once for read base word = ry*44 + 8*g (quad = (3ry+2g) mod 8),
// and each 16-lane phase covers each quad exactly twice -> conflict-free
// ds_read_b128 at any phase granularity. Lanes 50..63 inactive.
__constant__ int c_ryg[64] = {
    0x00, 0x13, 0x01, 0x10, 0x02, 0x11, 0x03, 0x12,
    0x04, 0x30, 0x22, 0x14, 0x23, 0x32, 0x20, 0x33,
    0x21, 0x34, 0x43, 0x31, 0x40, 0x53, 0x24, 0x50,
    0x42, 0x51, 0x60, 0x52, 0x44, 0x70, 0x41, 0x54,
    0x63, 0x72, 0x64, 0x73, 0x61, 0x74, 0x62, 0x71,
    0x80, 0x93, 0x81, 0x90, 0x82, 0x91, 0x83, 0x92,
    0x84, 0x94, 0,    0,    0,    0,    0,    0,
    0,    0,    0,    0,    0,    0,    0,    0};

// ---------------- setup ----------------

__global__ void k_copy(const float* __restrict__ src, float* __restrict__ dst,
                       long long n) {
    long long i0 = (long long)blockIdx.x * 256 + threadIdx.x;
    long long stride = (long long)gridDim.x * 256;
    for (long long i = i0; i < n; i += stride) dst[i] = src[i];
}

// transpose [O=32][I*9=288] -> [288][32]
__global__ void k_wtrans(const float* __restrict__ src, float* __restrict__ dst) {
    int idx = blockIdx.x * 256 + threadIdx.x;
    if (idx >= 9216) return;
    int o = idx / 288, r = idx % 288;
    dst[r * 32 + o] = src[idx];
}

__global__ void k_phitphi(const float* __restrict__ W, float* __restrict__ P) {
    int b = blockIdx.x * 16 + threadIdx.x;
    int a = blockIdx.y * 16 + threadIdx.y;
    float acc = 0.f;
    for (int k = 0; k < MDIM; ++k)
        acc += W[k * NDIM + a] * W[k * NDIM + b];
    P[(size_t)a * NDIM + b] = acc;
}

__global__ void k_wloss(const float* __restrict__ W, float* __restrict__ out) {
    int idx = blockIdx.x * 256 + threadIdx.x;
    if (idx >= MDIM * MDIM) return;
    int a = idx / MDIM, b = idx % MDIM;
    float acc = 0.f;
    for (int n = 0; n < NDIM; ++n)
        acc += W[a * NDIM + n] * W[b * NDIM + n];
    if (a == b) acc -= 1.f;
    out[idx] = acc;
}

__global__ void k_phitb(const float* __restrict__ y, const float* __restrict__ W,
                        float* __restrict__ PB) {
    int idx = blockIdx.x * 256 + threadIdx.x;
    if (idx >= NBP) return;
    int b = idx / NDIM, n = idx % NDIM;
    float acc = 0.f;
    for (int k = 0; k < MDIM; ++k)
        acc += y[b * MDIM + k] * W[k * NDIM + n];
    PB[idx] = acc;
}

// ---------------- X update ----------------

__global__ void k_x0(const float* __restrict__ PB, float* __restrict__ X1,
                     const float* __restrict__ hv) {
    int idx = blockIdx.x * 256 + threadIdx.x;
    if (idx >= NBP) return;
    X1[idx] = hv[0] * PB[idx];
}

// H = hatx = (1+tx)*Xc - tx*Xp
__global__ void k_hatx(const float* __restrict__ Xc, const float* __restrict__ Xp,
                       float* __restrict__ H, const float* __restrict__ txv,
                       int layer, int mode) {
    int idx = blockIdx.x * 256 + threadIdx.x;
    if (idx >= NBP) return;
    float tx = txv[layer];
    float xc = Xc[idx];
    float xp = (mode >= 2) ? Xp[idx] : 0.f;
    H[idx] = (1.f + tx) * xc - tx * xp;
}

// Xn = H*(1-h*b1) + h*PB - h*(H@P) + h*b1*Z - h*L
__global__ void k_xmm(const float* __restrict__ H, const float* __restrict__ P,
                      const float* __restrict__ PB, const float* __restrict__ Lc,
                      const float* __restrict__ Zc, float* __restrict__ Xn,
                      const float* __restrict__ hv, const float* __restrict__ b1v,
                      int layer, int mode) {
    __shared__ float As[64][17];
    __shared__ float Bs[16][65];
    int tid = threadIdx.x;
    float h = hv[layer], b1 = b1v[layer];
    int rowbase = blockIdx.y * 64, colbase = blockIdx.x * 64;
    int ttx = tid % 16, tty = tid / 16;
    float acc[4][4];
#pragma unroll
    for (int r = 0; r < 4; ++r)
#pragma unroll
        for (int c = 0; c < 4; ++c) acc[r][c] = 0.f;

    int am = tid >> 2, ak4 = (tid & 3) * 4;
    int bk = tid >> 4, bn4 = (tid & 15) * 4;

    for (int kt = 0; kt < 50; ++kt) {
        int k0 = kt * 16;
        {
            const float* hp = H + (size_t)(rowbase + am) * NDIM + k0 + ak4;
#pragma unroll
            for (int j = 0; j < 4; ++j) As[am][ak4 + j] = hp[j];
        }
        {
            const float* pr = P + (size_t)(k0 + bk) * NDIM + colbase + bn4;
#pragma unroll
            for (int j = 0; j < 4; ++j) {
                int col = colbase + bn4 + j;
                Bs[bk][bn4 + j] = (col < NDIM) ? pr[j] : 0.f;
            }
        }
        __syncthreads();
#pragma unroll
        for (int kk = 0; kk < 16; ++kk) {
            float a[4], b[4];
#pragma unroll
            for (int r = 0; r < 4; ++r) a[r] = As[tty * 4 + r][kk];
#pragma unroll
            for (int c = 0; c < 4; ++c) b[c] = Bs[kk][ttx * 4 + c];
#pragma unroll
            for (int r = 0; r < 4; ++r)
#pragma unroll
                for (int c = 0; c < 4; ++c) acc[r][c] += a[r] * b[c];
        }
        __syncthreads();
    }

#pragma unroll
    for (int r = 0; r < 4; ++r) {
        int row = rowbase + tty * 4 + r;
#pragma unroll
        for (int c = 0; c < 4; ++c) {
            int col = colbase + ttx * 4 + c;
            if (col >= NDIM) continue;
            size_t idx = (size_t)row * NDIM + col;
            float hx = H[idx];
            float zt = (mode == 2) ? Zc[idx] : 0.f;
            float lt = (mode == 2) ? Lc[idx] : 0.f;
            Xn[idx] = hx * (1.f - h * b1) + h * PB[idx] - h * acc[r][c] + h * b1 * zt - h * lt;
        }
    }
}

// ---------------- z_flat ----------------

__global__ void k_zflat(const float* __restrict__ Xn, const float* __restrict__ Zc,
                        const float* __restrict__ Zp, const float* __restrict__ Lc,
                        float* __restrict__ zf,
                        const float* __restrict__ hv, const float* __restrict__ b2v,
                        const float* __restrict__ tzv, int layer, int mode) {
    int idx = blockIdx.x * 256 + threadIdx.x;
    if (idx >= NBP) return;
    float h = hv[layer], b2 = b2v[layer], tz = tzv[layer];
    float hatz, lt;
    if (mode == 0) { hatz = 0.f; lt = 0.f; }
    else if (mode == 1) { hatz = (1.f + tz) * Zc[idx]; lt = 0.f; }
    else {
        float zc = Zc[idx], zp = Zp[idx];
        hatz = zc + tz * (zc - zp);
        lt = Lc[idx];
    }
    zf[idx] = hatz + h * (lt + b2 * (Xn[idx] - hatz));
}

// ---------------- convs (f32) ----------------
// v4: 512 threads = 8 waves, acc[4][8] (32 regs, no AGPR pressure).
// LDS tile: 16 ch x 12 rows x 44 words (stride 44, px x at word x+1,
// words 0,41..43 zero). Staging: one thread per row (tid<192): 10 aligned
// float4 global loads, register repack, 11 aligned ds_write_b128 (quad
// stride 11 coprime with 8 -> conflict-free writes). Compute: permuted
// lane map (c_ryg) -> conflict-free ds_read_b128. Per ci: 9 b128 reads
// feed 288 FMAs per wave. Accumulation order stays ci(0..31) -> ky -> kx.

__device__ __forceinline__ float4 soft4(float4 u, float thr) {
    float a;
    a = fabsf(u.x) - thr; u.x = (a > 0.f) ? copysignf(a, u.x) : 0.f;
    a = fabsf(u.y) - thr; u.y = (a > 0.f) ? copysignf(a, u.y) : 0.f;
    a = fabsf(u.z) - thr; u.z = (a > 0.f) ? copysignf(a, u.z) : 0.f;
    a = fabsf(u.w) - thr; u.w = (a > 0.f) ? copysignf(a, u.w) : 0.f;
    return u;
}

// stage one padded row (44 words) from global; gr<0/>=20 -> zero row
__device__ __forceinline__ void stage_row(const float* __restrict__ gsrc,
                                          float* __restrict__ ldsrow,
                                          int gr, int softflag, float thr) {
    float4* drow = reinterpret_cast<float4*>(ldsrow);
    if (gr >= 0 && gr < 20) {
        const float4* src = reinterpret_cast<const float4*>(gsrc);
        float4 a0 = src[0], a1 = src[1], a2 = src[2], a3 = src[3], a4 = src[4];
        if (softflag) {
            a0 = soft4(a0, thr); a1 = soft4(a1, thr); a2 = soft4(a2, thr);
            a3 = soft4(a3, thr); a4 = soft4(a4, thr);
        }
        drow[0] = make_float4(0.f,  a0.x, a0.y, a0.z);
        drow[1] = make_float4(a0.w, a1.x, a1.y, a1.z);
        drow[2] = make_float4(a1.w, a2.x, a2.y, a2.z);
        drow[3] = make_float4(a2.w, a3.x, a3.y, a3.z);
        drow[4] = make_float4(a3.w, a4.x, a4.y, a4.z);
        float carry = a4.w;
        a0 = src[5]; a1 = src[6]; a2 = src[7]; a3 = src[8]; a4 = src[9];
        if (softflag) {
            a0 = soft4(a0, thr); a1 = soft4(a1, thr); a2 = soft4(a2, thr);
            a3 = soft4(a3, thr); a4 = soft4(a4, thr);
        }
        drow[5] = make_float4(carry, a0.x, a0.y, a0.z);
        drow[6] = make_float4(a0.w,  a1.x, a1.y, a1.z);
        drow[7] = make_float4(a1.w,  a2.x, a2.y, a2.z);
        drow[8] = make_float4(a2.w,  a3.x, a3.y, a3.z);
        drow[9] = make_float4(a3.w,  a4.x, a4.y, a4.z);
        drow[10] = make_float4(a4.w, 0.f, 0.f, 0.f);
    } else {
        float4 z = make_float4(0.f, 0.f, 0.f, 0.f);
#pragma unroll
        for (int q = 0; q < 11; ++q) drow[q] = z;
    }
}

// 1->32 conv + relu. w: [32][1][3][3] raw. (cheap; unchanged structure)
__global__ void __launch_bounds__(512, 4)
k_conv1f(const float* __restrict__ zf, float* __restrict__ out,
         const float* __restrict__ w, int c0) {
    __shared__ float zs[22 * 42];
    int tid = threadIdx.x;
    int img = c0 + blockIdx.x;
    for (int i = tid; i < 22 * 42; i += 512) zs[i] = 0.f;
    __syncthreads();
    for (int p = tid; p < NPIX; p += 512) {
        int y = p / 40, x = p % 40;
        zs[(y + 1) * 42 + (x + 1)] = zf[(size_t)img * NPIX + p];
    }
    __syncthreads();

    int wv = __builtin_amdgcn_readfirstlane(tid >> 6);
    int ob = wv * 4;
    int lane = tid & 63;
    int ry = lane / 5;
    int xg = (lane % 5) * 8;
    bool active = lane < 50;

    float wreg[4][9];
#pragma unroll
    for (int oo = 0; oo < 4; ++oo)
#pragma unroll
        for (int q = 0; q < 9; ++q) wreg[oo][q] = w[(ob + oo) * 9 + q];

    if (active) {
#pragma unroll
        for (int half = 0; half < 2; ++half) {
            int orow = half * 10 + ry;
            float pv[3][10];
#pragma unroll
            for (int r = 0; r < 3; ++r)
#pragma unroll
                for (int j = 0; j < 10; ++j)
                    pv[r][j] = zs[(orow + r) * 42 + xg + j];
            float acc[4][8];
#pragma unroll
            for (int oo = 0; oo < 4; ++oo)
#pragma unroll
                for (int j = 0; j < 8; ++j) acc[oo][j] = 0.f;
#pragma unroll
            for (int ky = 0; ky < 3; ++ky)
#pragma unroll
                for (int kx = 0; kx < 3; ++kx) {
                    int q = ky * 3 + kx;
#pragma unroll
                    for (int j = 0; j < 8; ++j) {
                        float p = pv[ky][kx + j];
                        acc[0][j] += wreg[0][q] * p;
                        acc[1][j] += wreg[1][q] * p;
                        acc[2][j] += wreg[2][q] * p;
                        acc[3][j] += wreg[3][q] * p;
                    }
                }
#pragma unroll
            for (int oo = 0; oo < 4; ++oo) {
                float* op = out + (size_t)blockIdx.x * 25600 + (ob + oo) * 800
                            + orow * 40 + xg;
#pragma unroll
                for (int j = 0; j < 8; ++j) op[j] = fmaxf(acc[oo][j], 0.f);
            }
        }
    }
}

// 32->32 conv. wT: [ci*9+ky*3+kx][32 o]. Optional soft-threshold on input,
// relu on output. 8 waves x 4 och x 8 px, permuted lane map.
__global__ void __launch_bounds__(512, 6)
k_conv32(const float* __restrict__ in, float* __restrict__ out,
         const float* __restrict__ wT, const float* __restrict__ thrv,
         int layer, int softflag, int reluflag) {
    __shared__ alignas(16) float inS[16 * 12 * 44];   // 33792 B
    int tid = threadIdx.x;
    const float* ip = in + (size_t)blockIdx.x * 25600;
    float thr = softflag ? fabsf(thrv[layer]) : 0.f;

    int wv = __builtin_amdgcn_readfirstlane(tid >> 6);   // 0..7
    int ob = wv * 4;
    int lane = tid & 63;
    int code = c_ryg[lane];
    int ry = code >> 4;
    int xg = (code & 15) * 8;
    bool active = lane < 50;

    int sc = tid / 12, srr = tid - (tid / 12) * 12;   // staging row (tid<192)

    for (int half = 0; half < 2; ++half) {
        float acc[4][8];
#pragma unroll
        for (int oo = 0; oo < 4; ++oo)
#pragma unroll
            for (int j = 0; j < 8; ++j) acc[oo][j] = 0.f;

        for (int cg = 0; cg < 2; ++cg) {
            __syncthreads();   // prior compute done reading inS
            if (tid < 192) {
                int gr = half * 10 - 1 + srr;
                stage_row(ip + (size_t)(cg * 16 + sc) * 800 + gr * 40,
                          inS + sc * 528 + srr * 44, gr, softflag, thr);
            }
            __syncthreads();   // staged data visible

            if (active) {
#pragma unroll 1
                for (int ci = 0; ci < 16; ++ci) {
                    const float* rs = inS + ci * 528 + ry * 44 + xg;
                    const float* wc = wT + (size_t)(cg * 16 + ci) * 288 + ob;
#pragma unroll
                    for (int ky = 0; ky < 3; ++ky) {
                        const float4* rp =
                            reinterpret_cast<const float4*>(rs + ky * 44);
                        float4 u = rp[0], v2 = rp[1], w2 = rp[2];
                        float p[12];
                        p[0] = u.x;  p[1] = u.y;  p[2] = u.z;  p[3] = u.w;
                        p[4] = v2.x; p[5] = v2.y; p[6] = v2.z; p[7] = v2.w;
                        p[8] = w2.x; p[9] = w2.y; p[10] = w2.z; p[11] = w2.w;
#pragma unroll
                        for (int kx = 0; kx < 3; ++kx) {
                            int q = ky * 3 + kx;
                            float w0 = wc[q * 32 + 0];
                            float w1 = wc[q * 32 + 1];
                            float w2_ = wc[q * 32 + 2];
                            float w3 = wc[q * 32 + 3];
#pragma unroll
                            for (int j = 0; j < 8; ++j) {
                                float pj = p[kx + j];
                                acc[0][j] += w0 * pj;
                                acc[1][j] += w1 * pj;
                                acc[2][j] += w2_ * pj;
                                acc[3][j] += w3 * pj;
                            }
                        }
                    }
                }
            }
        }

        if (active) {
            int orow = half * 10 + ry;
#pragma unroll
            for (int oo = 0; oo < 4; ++oo) {
                float* op = out + (size_t)blockIdx.x * 25600 + (ob + oo) * 800
                            + orow * 40 + xg;
                float4 lo, hi;
                lo.x = acc[oo][0]; lo.y = acc[oo][1];
                lo.z = acc[oo][2]; lo.w = acc[oo][3];
                hi.x = acc[oo][4]; hi.y = acc[oo][5];
                hi.z = acc[oo][6]; hi.w = acc[oo][7];
                if (reluflag) {
                    lo.x = fmaxf(lo.x, 0.f); lo.y = fmaxf(lo.y, 0.f);
                    lo.z = fmaxf(lo.z, 0.f); lo.w = fmaxf(lo.w, 0.f);
                    hi.x = fmaxf(hi.x, 0.f); hi.y = fmaxf(hi.y, 0.f);
                    hi.z = fmaxf(hi.z, 0.f); hi.w = fmaxf(hi.w, 0.f);
                }
                reinterpret_cast<float4*>(op)[0] = lo;
                reinterpret_cast<float4*>(op)[1] = hi;
            }
        }
    }
}

// 32->1 conv; writes f32 to global output; optional -z_in.
// 8 waves; wave wv owns local channels {2wv, 2wv+1} of each 16-ch group
// (4 global ci total); partial sums reduced through LDS (aliased on inS).
__global__ void __launch_bounds__(512, 6)
k_conv2b(const float* __restrict__ in, const float* __restrict__ w,
         const float* __restrict__ zf, float* __restrict__ out,
         int subz, int c0) {
    __shared__ alignas(16) float inS[16 * 12 * 44];   // head reused as psum
    float* psum = inS;
    int tid = threadIdx.x;
    int img = c0 + blockIdx.x;
    const float* ip = in + (size_t)blockIdx.x * 25600;

    int wv = __builtin_amdgcn_readfirstlane(tid >> 6);
    int lane = tid & 63;
    int code = c_ryg[lane];
    int ry = code >> 4;
    int xg = (code & 15) * 8;
    bool active = lane < 50;

    int sc = tid / 12, srr = tid - (tid / 12) * 12;

    for (int half = 0; half < 2; ++half) {
        float acc[8];
#pragma unroll
        for (int j = 0; j < 8; ++j) acc[j] = 0.f;

        for (int cg = 0; cg < 2; ++cg) {
            __syncthreads();   // prior reads of inS (compute/reduce) done
            if (tid < 192) {
                int gr = half * 10 - 1 + srr;
                stage_row(ip + (size_t)(cg * 16 + sc) * 800 + gr * 40,
                          inS + sc * 528 + srr * 44, gr, 0, 0.f);
            }
            __syncthreads();

            if (active) {
#pragma unroll
                for (int k = 0; k < 2; ++k) {
                    int cil = wv * 2 + k;   // 0..15
                    const float* rs = inS + cil * 528 + ry * 44 + xg;
                    const float* wc = w + (size_t)(cg * 16 + cil) * 9;
#pragma unroll
                    for (int ky = 0; ky < 3; ++ky) {
                        const float4* rp =
                            reinterpret_cast<const float4*>(rs + ky * 44);
                        float4 u = rp[0], v2 = rp[1], w2 = rp[2];
                        float p[12];
                        p[0] = u.x;  p[1] = u.y;  p[2] = u.z;  p[3] = u.w;
                        p[4] = v2.x; p[5] = v2.y; p[6] = v2.z; p[7] = v2.w;
                        p[8] = w2.x; p[9] = w2.y; p[10] = w2.z; p[11] = w2.w;
#pragma unroll
                        for (int kx = 0; kx < 3; ++kx) {
                            float wq = wc[ky * 3 + kx];
#pragma unroll
                            for (int j = 0; j < 8; ++j)
                                acc[j] += wq * p[kx + j];
                        }
                    }
                }
            }
        }

        __syncthreads();   // all compute reads of inS done -> reuse as psum
        if (active) {
#pragma unroll
            for (int j = 0; j < 8; ++j)
                psum[wv * 400 + ry * 40 + xg + j] = acc[j];
        }
        __syncthreads();
        for (int p = tid; p < 400; p += 512) {
            float s = 0.f;
#pragma unroll
            for (int u = 0; u < 8; ++u) s += psum[u * 400 + p];
            size_t gidx = (size_t)img * NPIX + half * 400 + p;
            if (subz) s -= zf[gidx];
            out[gidx] = s;
        }
        __syncthreads();
    }
}

// ---------------- L update ----------------

__global__ void k_lup(const float* __restrict__ Xn, const float* __restrict__ Zn,
                      const float* __restrict__ Lc, const float* __restrict__ Lp,
                      float* __restrict__ Ln,
                      const float* __restrict__ hv, const float* __restrict__ b1v,
                      const float* __restrict__ tLv, int layer, int mode) {
    int idx = blockIdx.x * 256 + threadIdx.x;
    if (idx >= NBP) return;
    float h = hv[layer], b1 = b1v[layer], tL = tLv[layer];
    float hatL;
    if (mode == 0) hatL = 0.f;
    else if (mode == 1) hatL = (1.f + tL) * Lc[idx];
    else {
        float lc = Lc[idx], lp = Lp[idx];
        hatL = lc + tL * (lc - lp);
    }
    Ln[idx] = hatL + h * b1 * (Xn[idx] - Zn[idx]);
}

// ---------------- host ----------------
// PROBE-VERIFIED (round 5): inputs f32, dict order, n_in=14, output f32, ws>=120MB.

extern "C" void kernel_launch(void* const* d_in, const int* in_sizes, int n_in,
                              void* d_out, int out_size, void* d_ws, size_t ws_size,
                              hipStream_t stream) {
    const float* y    = (const float*)d_in[0];
    const float* Wf   = (const float*)d_in[2];
    const float* b1v  = (const float*)d_in[3];
    const float* b2v  = (const float*)d_in[4];
    const float* hv   = (const float*)d_in[5];
    const float* stv  = (const float*)d_in[6];
    const float* txv  = (const float*)d_in[7];
    const float* tzv  = (const float*)d_in[8];
    const float* tLv  = (const float*)d_in[9];
    const float* w1f  = (const float*)d_in[10];
    const float* w2f  = (const float*)d_in[11];
    const float* w1b  = (const float*)d_in[12];
    const float* w2b  = (const float*)d_in[13];

    float* Zout  = (float*)d_out;                       // [9][NBP]
    float* Sout  = Zout + (size_t)NLAYERS * NBP;        // [9][NBP]
    float* WLout = Zout + 2 * (size_t)NLAYERS * NBP;    // [327*327]

    char* ws = (char*)d_ws;
    size_t off = 0;
    auto alloc = [&](size_t bytes) -> void* {
        void* p = ws + off;
        off += (bytes + 255) & ~(size_t)255;
        return p;
    };

    float* w2fT = (float*)alloc(9216 * 4);
    float* w1bT = (float*)alloc(9216 * 4);
    float* P    = (float*)alloc((size_t)NDIM * NDIM * 4);
    float* PB   = (float*)alloc((size_t)NBP * 4);
    float* Xa   = (float*)alloc((size_t)NBP * 4);
    float* Xb_  = (float*)alloc((size_t)NBP * 4);
    float* La   = (float*)alloc((size_t)NBP * 4);
    float* Lb_  = (float*)alloc((size_t)NBP * 4);
    float* zfb  = (float*)alloc((size_t)NBP * 4);   // doubles as hatx temp

    size_t rem = (ws_size > off + 4096) ? (ws_size - off - 4096) : 0;
    long long Ci = (long long)(rem / (2 * 25600 * 4));
    if (Ci > 2048) Ci = 2048;
    if (Ci < 1) Ci = 1;
    int C = (int)Ci;
    float* Abuf = (float*)alloc((size_t)C * 25600 * 4);
    float* Bbuf = (float*)alloc((size_t)C * 25600 * 4);

    int ew_grid = (NBP + 255) / 256;

    k_wtrans<<<36, 256, 0, stream>>>(w2f, w2fT);
    k_wtrans<<<36, 256, 0, stream>>>(w1b, w1bT);
    k_phitphi<<<dim3(50, 50), dim3(16, 16), 0, stream>>>(Wf, P);
    k_wloss<<<(MDIM * MDIM + 255) / 256, 256, 0, stream>>>(Wf, WLout);
    k_phitb<<<ew_grid, 256, 0, stream>>>(y, Wf, PB);

    float* Xcur = Xa; float* Xoth = Xb_;
    float* Lcur = La; float* Loth = Lb_;

    for (int i = 0; i < NLAYERS; ++i) {
        int mode = (i == 0) ? 0 : ((i == 1) ? 1 : 2);
        float* Zw = Zout + (size_t)i * NBP;
        const float* Zc = Zout + (size_t)((i >= 1) ? (i - 1) : 0) * NBP;
        const float* Zp = Zout + (size_t)((i >= 2) ? (i - 2) : 0) * NBP;

        float* Xn;
        if (i == 0) {
            Xn = Xcur;
            k_x0<<<ew_grid, 256, 0, stream>>>(PB, Xn, hv);
        } else {
            k_hatx<<<ew_grid, 256, 0, stream>>>(Xcur, Xoth, zfb, txv, i, mode);
            Xn = Xoth;
            k_xmm<<<dim3(13, 64), 256, 0, stream>>>(zfb, P, PB, Lcur, Zc, Xn,
                                                    hv, b1v, i, mode);
            float* t = Xcur; Xcur = Xn; Xoth = t;
        }

        k_zflat<<<ew_grid, 256, 0, stream>>>(Xn, Zc, Zp, Lcur, zfb, hv, b2v, tzv, i, mode);

        for (int c0 = 0; c0 < NB; c0 += C) {
            int g = (NB - c0 < C) ? (NB - c0) : C;
            k_conv1f<<<g, 512, 0, stream>>>(zfb, Abuf, w1f, c0);
            k_conv32<<<g, 512, 0, stream>>>(Abuf, Bbuf, w2fT, stv, i, 0, 0);   // x_fwd
            k_conv32<<<g, 512, 0, stream>>>(Bbuf, Abuf, w1bT, stv, i, 1, 1);   // relu(c1b(soft(x_fwd)))
            k_conv2b<<<g, 512, 0, stream>>>(Abuf, w2b, zfb, Zw, 0, c0);        // Zs[i]
            k_conv32<<<g, 512, 0, stream>>>(Bbuf, Abuf, w1bT, stv, i, 0, 1);   // relu(c1b(x_fwd))
            k_conv2b<<<g, 512, 0, stream>>>(Abuf, w2b, zfb, Sout + (size_t)i * NBP, 1, c0); // syms[i]
        }

        k_lup<<<ew_grid, 256, 0, stream>>>(Xn, Zw, Lcur, Loth, Loth, hv, b1v, tLv, i, mode);
        { float* t = Lcur; Lcur = Loth; Loth = t; }
    }
}

// Round 5
// 14137.315 us; speedup vs baseline: 2.3097x; 1.8170x over previous
//
#include <hip/hip_runtime.h>
#include <hip/hip_bf16.h>

#define NB 4096
#define MDIM 327
#define NDIM 800
#define NLAYERS 9
#define NPIX 800
#define CHN 32
#define NBP (NB * NPIX)

typedef __hip_bfloat16 bf16;

typedef __attribute__((ext_vector_type(4))) short short4v;
typedef __attribute__((ext_vector_type(8))) short short8v;
typedef __attribute__((ext_vector_type(4))) float float4v;

#if defined(__has_builtin)
#if __has_builtin(__builtin_amdgcn_mfma_f32_16x16x16bf16_1k)
#define HAVE_MFMA16 1
#endif
#endif

// two K=16 MFMAs (or one K=32 on fallback): c += A(kh0)B(kh0) + A(kh1)B(kh1)
__device__ __forceinline__ float4v mfma2(short4v a0, short4v a1,
                                         short4v b0, short4v b1, float4v c) {
#ifdef HAVE_MFMA16
    c = __builtin_amdgcn_mfma_f32_16x16x16bf16_1k(a0, b0, c, 0, 0, 0);
    c = __builtin_amdgcn_mfma_f32_16x16x16bf16_1k(a1, b1, c, 0, 0, 0);
    return c;
#else
    typedef __attribute__((ext_vector_type(8))) __bf16 bf16x8;
    short8v A = __builtin_shufflevector(a0, a1, 0, 1, 2, 3, 4, 5, 6, 7);
    short8v B = __builtin_shufflevector(b0, b1, 0, 1, 2, 3, 4, 5, 6, 7);
    return __builtin_amdgcn_mfma_f32_16x16x32_bf16(
        __builtin_bit_cast(bf16x8, A), __builtin_bit_cast(bf16x8, B), c, 0, 0, 0);
#endif
}

__device__ __forceinline__ unsigned short f2bf(float f) {
    unsigned int u = __float_as_uint(f);
    unsigned int r = u + 0x7FFFu + ((u >> 16) & 1u);
    return (unsigned short)(r >> 16);
}
__device__ __forceinline__ float bf2f(unsigned short h) {
    return __uint_as_float(((unsigned int)h) << 16);
}

// Permuted lane -> (ry, xgroup) map for conv2b (kept from r4).
__constant__ int c_ryg[64] = {
    0x00, 0x13, 0x01, 0x10, 0x02, 0x11, 0x03, 0x12,
    0x04, 0x30, 0x22, 0x14, 0x23, 0x32, 0x20, 0x33,
    0x21, 0x34, 0x43, 0x31, 0x40, 0x53, 0x24, 0x50,
    0x42, 0x51, 0x60, 0x52, 0x44, 0x70, 0x41, 0x54,
    0x63, 0x72, 0x64, 0x73, 0x61, 0x74, 0x62, 0x71,
    0x80, 0x93, 0x81, 0x90, 0x82, 0x91, 0x83, 0x92,
    0x84, 0x94, 0,    0,    0,    0,    0,    0,
    0,    0,    0,    0,    0,    0,    0,    0};

// ---------------- setup ----------------

__global__ void k_phitphi(const float* __restrict__ W, float* __restrict__ P) {
    int b = blockIdx.x * 16 + threadIdx.x;
    int a = blockIdx.y * 16 + threadIdx.y;
    float acc = 0.f;
    for (int k = 0; k < MDIM; ++k)
        acc += W[k * NDIM + a] * W[k * NDIM + b];
    P[(size_t)a * NDIM + b] = acc;
}

__global__ void k_wloss(const float* __restrict__ W, float* __restrict__ out) {
    int idx = blockIdx.x * 256 + threadIdx.x;
    if (idx >= MDIM * MDIM) return;
    int a = idx / MDIM, b = idx % MDIM;
    float acc = 0.f;
    for (int n = 0; n < NDIM; ++n)
        acc += W[a * NDIM + n] * W[b * NDIM + n];
    if (a == b) acc -= 1.f;
    out[idx] = acc;
}

__global__ void k_phitb(const float* __restrict__ y, const float* __restrict__ W,
                        float* __restrict__ PB) {
    int idx = blockIdx.x * 256 + threadIdx.x;
    if (idx >= NBP) return;
    int b = idx / NDIM, n = idx % NDIM;
    float acc = 0.f;
    for (int k = 0; k < MDIM; ++k)
        acc += y[b * MDIM + k] * W[k * NDIM + n];
    PB[idx] = acc;
}

// Pack conv weights [32 o][32 i][3][3] f32 into MFMA A-fragment order, split
// hi/lo bf16. Layout: slot = ((q*2+term)*2+oh)*2+kh (q=tap 0..8), entry
// [slot][lane] = 4 bf16 = W_term[och = oh*16 + (lane&15)]
//                          [ci = kh*16 + (lane>>4)*4 + j][tap q].
__global__ void k_wpack(const float* __restrict__ w, unsigned short* __restrict__ out) {
    int idx = blockIdx.x * 256 + threadIdx.x;
    if (idx >= 72 * 64) return;
    int lane = idx & 63, slot = idx >> 6;
    int kh = slot & 1, oh = (slot >> 1) & 1, term = (slot >> 2) & 1, q = slot >> 3;
    int och = oh * 16 + (lane & 15);
    int cib = kh * 16 + (lane >> 4) * 4;
    short4v r;
#pragma unroll
    for (int j = 0; j < 4; ++j) {
        float v = w[och * 288 + (cib + j) * 9 + q];
        unsigned short h = f2bf(v);
        unsigned short e = term ? f2bf(v - bf2f(h)) : h;
        r[j] = (short)e;
    }
    reinterpret_cast<short4v*>(out)[slot * 64 + lane] = r;
}

// ---------------- X update ----------------

__global__ void k_x0(const float* __restrict__ PB, float* __restrict__ X1,
                     const float* __restrict__ hv) {
    int idx = blockIdx.x * 256 + threadIdx.x;
    if (idx >= NBP) return;
    X1[idx] = hv[0] * PB[idx];
}

__global__ void k_hatx(const float* __restrict__ Xc, const float* __restrict__ Xp,
                       float* __restrict__ H, const float* __restrict__ txv,
                       int layer, int mode) {
    int idx = blockIdx.x * 256 + threadIdx.x;
    if (idx >= NBP) return;
    float tx = txv[layer];
    float xc = Xc[idx];
    float xp = (mode >= 2) ? Xp[idx] : 0.f;
    H[idx] = (1.f + tx) * xc - tx * xp;
}

__global__ void k_xmm(const float* __restrict__ H, const float* __restrict__ P,
                      const float* __restrict__ PB, const float* __restrict__ Lc,
                      const float* __restrict__ Zc, float* __restrict__ Xn,
                      const float* __restrict__ hv, const float* __restrict__ b1v,
                      int layer, int mode) {
    __shared__ float As[64][17];
    __shared__ float Bs[16][65];
    int tid = threadIdx.x;
    float h = hv[layer], b1 = b1v[layer];
    int rowbase = blockIdx.y * 64, colbase = blockIdx.x * 64;
    int ttx = tid % 16, tty = tid / 16;
    float acc[4][4];
#pragma unroll
    for (int r = 0; r < 4; ++r)
#pragma unroll
        for (int c = 0; c < 4; ++c) acc[r][c] = 0.f;

    int am = tid >> 2, ak4 = (tid & 3) * 4;
    int bk = tid >> 4, bn4 = (tid & 15) * 4;

    for (int kt = 0; kt < 50; ++kt) {
        int k0 = kt * 16;
        {
            const float* hp = H + (size_t)(rowbase + am) * NDIM + k0 + ak4;
#pragma unroll
            for (int j = 0; j < 4; ++j) As[am][ak4 + j] = hp[j];
        }
        {
            const float* pr = P + (size_t)(k0 + bk) * NDIM + colbase + bn4;
#pragma unroll
            for (int j = 0; j < 4; ++j) {
                int col = colbase + bn4 + j;
                Bs[bk][bn4 + j] = (col < NDIM) ? pr[j] : 0.f;
            }
        }
        __syncthreads();
#pragma unroll
        for (int kk = 0; kk < 16; ++kk) {
            float a[4], b[4];
#pragma unroll
            for (int r = 0; r < 4; ++r) a[r] = As[tty * 4 + r][kk];
#pragma unroll
            for (int c = 0; c < 4; ++c) b[c] = Bs[kk][ttx * 4 + c];
#pragma unroll
            for (int r = 0; r < 4; ++r)
#pragma unroll
                for (int c = 0; c < 4; ++c) acc[r][c] += a[r] * b[c];
        }
        __syncthreads();
    }

#pragma unroll
    for (int r = 0; r < 4; ++r) {
        int row = rowbase + tty * 4 + r;
#pragma unroll
        for (int c = 0; c < 4; ++c) {
            int col = colbase + ttx * 4 + c;
            if (col >= NDIM) continue;
            size_t idx = (size_t)row * NDIM + col;
            float hx = H[idx];
            float zt = (mode == 2) ? Zc[idx] : 0.f;
            float lt = (mode == 2) ? Lc[idx] : 0.f;
            Xn[idx] = hx * (1.f - h * b1) + h * PB[idx] - h * acc[r][c] + h * b1 * zt - h * lt;
        }
    }
}

// ---------------- z_flat ----------------

__global__ void k_zflat(const float* __restrict__ Xn, const float* __restrict__ Zc,
                        const float* __restrict__ Zp, const float* __restrict__ Lc,
                        float* __restrict__ zf,
                        const float* __restrict__ hv, const float* __restrict__ b2v,
                        const float* __restrict__ tzv, int layer, int mode) {
    int idx = blockIdx.x * 256 + threadIdx.x;
    if (idx >= NBP) return;
    float h = hv[layer], b2 = b2v[layer], tz = tzv[layer];
    float hatz, lt;
    if (mode == 0) { hatz = 0.f; lt = 0.f; }
    else if (mode == 1) { hatz = (1.f + tz) * Zc[idx]; lt = 0.f; }
    else {
        float zc = Zc[idx], zp = Zp[idx];
        hatz = zc + tz * (zc - zp);
        lt = Lc[idx];
    }
    zf[idx] = hatz + h * (lt + b2 * (Xn[idx] - hatz));
}

// ---------------- convs ----------------

__device__ __forceinline__ float4 soft4(float4 u, float thr) {
    float a;
    a = fabsf(u.x) - thr; u.x = (a > 0.f) ? copysignf(a, u.x) : 0.f;
    a = fabsf(u.y) - thr; u.y = (a > 0.f) ? copysignf(a, u.y) : 0.f;
    a = fabsf(u.z) - thr; u.z = (a > 0.f) ? copysignf(a, u.z) : 0.f;
    a = fabsf(u.w) - thr; u.w = (a > 0.f) ? copysignf(a, u.w) : 0.f;
    return u;
}

// stage one padded f32 row (44 words) from global (conv2b helper, from r4)
__device__ __forceinline__ void stage_row(const float* __restrict__ gsrc,
                                          float* __restrict__ ldsrow,
                                          int gr, int softflag, float thr) {
    float4* drow = reinterpret_cast<float4*>(ldsrow);
    if (gr >= 0 && gr < 20) {
        const float4* src = reinterpret_cast<const float4*>(gsrc);
        float4 a0 = src[0], a1 = src[1], a2 = src[2], a3 = src[3], a4 = src[4];
        if (softflag) {
            a0 = soft4(a0, thr); a1 = soft4(a1, thr); a2 = soft4(a2, thr);
            a3 = soft4(a3, thr); a4 = soft4(a4, thr);
        }
        drow[0] = make_float4(0.f,  a0.x, a0.y, a0.z);
        drow[1] = make_float4(a0.w, a1.x, a1.y, a1.z);
        drow[2] = make_float4(a1.w, a2.x, a2.y, a2.z);
        drow[3] = make_float4(a2.w, a3.x, a3.y, a3.z);
        drow[4] = make_float4(a3.w, a4.x, a4.y, a4.z);
        float carry = a4.w;
        a0 = src[5]; a1 = src[6]; a2 = src[7]; a3 = src[8]; a4 = src[9];
        if (softflag) {
            a0 = soft4(a0, thr); a1 = soft4(a1, thr); a2 = soft4(a2, thr);
            a3 = soft4(a3, thr); a4 = soft4(a4, thr);
        }
        drow[5] = make_float4(carry, a0.x, a0.y, a0.z);
        drow[6] = make_float4(a0.w,  a1.x, a1.y, a1.z);
        drow[7] = make_float4(a1.w,  a2.x, a2.y, a2.z);
        drow[8] = make_float4(a2.w,  a3.x, a3.y, a3.z);
        drow[9] = make_float4(a3.w,  a4.x, a4.y, a4.z);
        drow[10] = make_float4(a4.w, 0.f, 0.f, 0.f);
    } else {
        float4 z = make_float4(0.f, 0.f, 0.f, 0.f);
#pragma unroll
        for (int q = 0; q < 11; ++q) drow[q] = z;
    }
}

// 1->32 conv + relu. w: [32][1][3][3] raw. (unchanged)
__global__ void __launch_bounds__(512, 4)
k_conv1f(const float* __restrict__ zf, float* __restrict__ out,
         const float* __restrict__ w, int c0) {
    __shared__ float zs[22 * 42];
    int tid = threadIdx.x;
    int img = c0 + blockIdx.x;
    for (int i = tid; i < 22 * 42; i += 512) zs[i] = 0.f;
    __syncthreads();
    for (int p = tid; p < NPIX; p += 512) {
        int y = p / 40, x = p % 40;
        zs[(y + 1) * 42 + (x + 1)] = zf[(size_t)img * NPIX + p];
    }
    __syncthreads();

    int wv = __builtin_amdgcn_readfirstlane(tid >> 6);
    int ob = wv * 4;
    int lane = tid & 63;
    int ry = lane / 5;
    int xg = (lane % 5) * 8;
    bool active = lane < 50;

    float wreg[4][9];
#pragma unroll
    for (int oo = 0; oo < 4; ++oo)
#pragma unroll
        for (int q = 0; q < 9; ++q) wreg[oo][q] = w[(ob + oo) * 9 + q];

    if (active) {
#pragma unroll
        for (int half = 0; half < 2; ++half) {
            int orow = half * 10 + ry;
            float pv[3][10];
#pragma unroll
            for (int r = 0; r < 3; ++r)
#pragma unroll
                for (int j = 0; j < 10; ++j)
                    pv[r][j] = zs[(orow + r) * 42 + xg + j];
            float acc[4][8];
#pragma unroll
            for (int oo = 0; oo < 4; ++oo)
#pragma unroll
                for (int j = 0; j < 8; ++j) acc[oo][j] = 0.f;
#pragma unroll
            for (int ky = 0; ky < 3; ++ky)
#pragma unroll
                for (int kx = 0; kx < 3; ++kx) {
                    int q = ky * 3 + kx;
#pragma unroll
                    for (int j = 0; j < 8; ++j) {
                        float p = pv[ky][kx + j];
                        acc[0][j] += wreg[0][q] * p;
                        acc[1][j] += wreg[1][q] * p;
                        acc[2][j] += wreg[2][q] * p;
                        acc[3][j] += wreg[3][q] * p;
                    }
                }
#pragma unroll
            for (int oo = 0; oo < 4; ++oo) {
                float* op = out + (size_t)blockIdx.x * 25600 + (ob + oo) * 800
                            + orow * 40 + xg;
#pragma unroll
                for (int j = 0; j < 8; ++j) op[j] = fmaxf(acc[oo][j], 0.f);
            }
        }
    }
}

// 32->32 conv via MFMA (split-bf16, 4 terms). 3 blocks per image, each owns
// 8 output rows (last: 4). LDS: 420 padded positions x 144B:
//   [hi: 4 chunks of 16B][lo: 4 chunks][16B pad], chunk b holds
//   bf16 of ci {4b..4b+3, 16+4b..16+4b+3} -> one ds_read_b128 = full B-frag.
// Quad stride 9 (coprime 8) -> conflict-free. 8 waves = 2 och-halves x 4
// px-tile groups; each wave: A-frags (72 VGPR) + acc(4) per 16-px tile.
__global__ void __launch_bounds__(512, 4)
k_conv32m(const float* __restrict__ in, float* __restrict__ out,
          const unsigned short* __restrict__ Wpk, const float* __restrict__ thrv,
          int layer, int softflag, int reluflag) {
    __shared__ alignas(16) unsigned short XS[420 * 72];   // 60480 B
    int tid = threadIdx.x;
    int bx = blockIdx.x;
    int img = bx / 3, chunk = bx - img * 3;
    const float* ip = in + (size_t)img * 25600;
    float thr = softflag ? fabsf(thrv[layer]) : 0.f;

    int wv = __builtin_amdgcn_readfirstlane(tid >> 6);   // 0..7
    int oh = wv & 1;        // och half
    int grp = wv >> 1;      // px tile group
    int lane = tid & 63;
    int l15 = lane & 15, bq = lane >> 4;

    // ---- stage: one thread per padded position ----
    int row0 = chunk * 8 - 1;
    if (tid < 420) {
        int r = tid / 42, c = tid - r * 42;
        int gr = row0 + r, gc = c - 1;
        unsigned short* dst = XS + tid * 72;
        short8v* d8 = reinterpret_cast<short8v*>(dst);
        if (gr >= 0 && gr < 20 && gc >= 0 && gc < 40) {
            float v[32];
#pragma unroll
            for (int ci = 0; ci < 32; ++ci)
                v[ci] = ip[(size_t)ci * 800 + gr * 40 + gc];
            if (softflag) {
#pragma unroll
                for (int ci = 0; ci < 32; ++ci) {
                    float a = fabsf(v[ci]) - thr;
                    v[ci] = (a > 0.f) ? copysignf(a, v[ci]) : 0.f;
                }
            }
#pragma unroll
            for (int b = 0; b < 4; ++b) {
                short8v ph, pl;
#pragma unroll
                for (int j = 0; j < 8; ++j) {
                    int ci = (j < 4) ? (4 * b + j) : (16 + 4 * b + (j - 4));
                    unsigned short h = f2bf(v[ci]);
                    ph[j] = (short)h;
                    pl[j] = (short)f2bf(v[ci] - bf2f(h));
                }
                d8[b] = ph;
                d8[4 + b] = pl;
            }
        } else {
            short8v z = {0, 0, 0, 0, 0, 0, 0, 0};
#pragma unroll
            for (int b = 0; b < 8; ++b) d8[b] = z;
        }
    }
    __syncthreads();

    // ---- load A fragments (after barrier to cap register pressure) ----
    const short4v* wp4 = reinterpret_cast<const short4v*>(Wpk);
    short4v ah[9][2], al[9][2];
#pragma unroll
    for (int q = 0; q < 9; ++q)
#pragma unroll
        for (int kh = 0; kh < 2; ++kh) {
            ah[q][kh] = wp4[(q * 8 + oh * 2 + kh) * 64 + lane];
            al[q][kh] = wp4[(q * 8 + 4 + oh * 2 + kh) * 64 + lane];
        }

    int R = 20 - chunk * 8; if (R > 8) R = 8;
    int ntiles = R * 40 / 16;   // 20 or 10

    for (int t = grp; t < ntiles; t += 4) {
        int p = t * 16 + l15;
        int y = (p * 205) >> 13;       // p/40 for p<320
        int x = p - y * 40;
        int pos = (y + 1) * 42 + (x + 1);
        const unsigned short* bp = XS + (pos * 72 + bq * 8 - 3096);

        float4v accE = {0.f, 0.f, 0.f, 0.f};
        float4v accO = {0.f, 0.f, 0.f, 0.f};
#pragma unroll
        for (int ky = 0; ky < 3; ++ky)
#pragma unroll
            for (int kx = 0; kx < 3; ++kx) {
                int q = ky * 3 + kx;
                int toff = (ky * 42 + kx) * 72;
                short8v bh = *reinterpret_cast<const short8v*>(bp + toff);
                short8v bl = *reinterpret_cast<const short8v*>(bp + toff + 32);
                short4v bh0 = __builtin_shufflevector(bh, bh, 0, 1, 2, 3);
                short4v bh1 = __builtin_shufflevector(bh, bh, 4, 5, 6, 7);
                short4v bl0 = __builtin_shufflevector(bl, bl, 0, 1, 2, 3);
                short4v bl1 = __builtin_shufflevector(bl, bl, 4, 5, 6, 7);
                accE = mfma2(ah[q][0], ah[q][1], bh0, bh1, accE);  // Wh*Xh
                accE = mfma2(ah[q][0], ah[q][1], bl0, bl1, accE);  // Wh*Xl
                accO = mfma2(al[q][0], al[q][1], bh0, bh1, accO);  // Wl*Xh
                accO = mfma2(al[q][0], al[q][1], bl0, bl1, accO);  // Wl*Xl
            }

        int gpx = chunk * 320 + p;
        float* op = out + (size_t)img * 25600 + (size_t)(oh * 16 + bq * 4) * 800 + gpx;
#pragma unroll
        for (int r = 0; r < 4; ++r) {
            float vv = accE[r] + accO[r];
            if (reluflag) vv = fmaxf(vv, 0.f);
            op[(size_t)r * 800] = vv;
        }
    }
}

// 32->1 conv (unchanged from r4): f32 vector path, permuted lane map.
__global__ void __launch_bounds__(512, 6)
k_conv2b(const float* __restrict__ in, const float* __restrict__ w,
         const float* __restrict__ zf, float* __restrict__ out,
         int subz, int c0) {
    __shared__ alignas(16) float inS[16 * 12 * 44];   // head reused as psum
    float* psum = inS;
    int tid = threadIdx.x;
    int img = c0 + blockIdx.x;
    const float* ip = in + (size_t)blockIdx.x * 25600;

    int wv = __builtin_amdgcn_readfirstlane(tid >> 6);
    int lane = tid & 63;
    int code = c_ryg[lane];
    int ry = code >> 4;
    int xg = (code & 15) * 8;
    bool active = lane < 50;

    int sc = tid / 12, srr = tid - (tid / 12) * 12;

    for (int half = 0; half < 2; ++half) {
        float acc[8];
#pragma unroll
        for (int j = 0; j < 8; ++j) acc[j] = 0.f;

        for (int cg = 0; cg < 2; ++cg) {
            __syncthreads();
            if (tid < 192) {
                int gr = half * 10 - 1 + srr;
                stage_row(ip + (size_t)(cg * 16 + sc) * 800 + gr * 40,
                          inS + sc * 528 + srr * 44, gr, 0, 0.f);
            }
            __syncthreads();

            if (active) {
#pragma unroll
                for (int k = 0; k < 2; ++k) {
                    int cil = wv * 2 + k;
                    const float* rs = inS + cil * 528 + ry * 44 + xg;
                    const float* wc = w + (size_t)(cg * 16 + cil) * 9;
#pragma unroll
                    for (int ky = 0; ky < 3; ++ky) {
                        const float4* rp =
                            reinterpret_cast<const float4*>(rs + ky * 44);
                        float4 u = rp[0], v2 = rp[1], w2 = rp[2];
                        float p[12];
                        p[0] = u.x;  p[1] = u.y;  p[2] = u.z;  p[3] = u.w;
                        p[4] = v2.x; p[5] = v2.y; p[6] = v2.z; p[7] = v2.w;
                        p[8] = w2.x; p[9] = w2.y; p[10] = w2.z; p[11] = w2.w;
#pragma unroll
                        for (int kx = 0; kx < 3; ++kx) {
                            float wq = wc[ky * 3 + kx];
#pragma unroll
                            for (int j = 0; j < 8; ++j)
                                acc[j] += wq * p[kx + j];
                        }
                    }
                }
            }
        }

        __syncthreads();
        if (active) {
#pragma unroll
            for (int j = 0; j < 8; ++j)
                psum[wv * 400 + ry * 40 + xg + j] = acc[j];
        }
        __syncthreads();
        for (int p = tid; p < 400; p += 512) {
            float s = 0.f;
#pragma unroll
            for (int u = 0; u < 8; ++u) s += psum[u * 400 + p];
            size_t gidx = (size_t)img * NPIX + half * 400 + p;
            if (subz) s -= zf[gidx];
            out[gidx] = s;
        }
        __syncthreads();
    }
}

// ---------------- L update ----------------

__global__ void k_lup(const float* __restrict__ Xn, const float* __restrict__ Zn,
                      const float* __restrict__ Lc, const float* __restrict__ Lp,
                      float* __restrict__ Ln,
                      const float* __restrict__ hv, const float* __restrict__ b1v,
                      const float* __restrict__ tLv, int layer, int mode) {
    int idx = blockIdx.x * 256 + threadIdx.x;
    if (idx >= NBP) return;
    float h = hv[layer], b1 = b1v[layer], tL = tLv[layer];
    float hatL;
    if (mode == 0) hatL = 0.f;
    else if (mode == 1) hatL = (1.f + tL) * Lc[idx];
    else {
        float lc = Lc[idx], lp = Lp[idx];
        hatL = lc + tL * (lc - lp);
    }
    Ln[idx] = hatL + h * b1 * (Xn[idx] - Zn[idx]);
}

// ---------------- host ----------------
// PROBE-VERIFIED (round 5): inputs f32, dict order, n_in=14, output f32, ws>=120MB.

extern "C" void kernel_launch(void* const* d_in, const int* in_sizes, int n_in,
                              void* d_out, int out_size, void* d_ws, size_t ws_size,
                              hipStream_t stream) {
    const float* y    = (const float*)d_in[0];
    const float* Wf   = (const float*)d_in[2];
    const float* b1v  = (const float*)d_in[3];
    const float* b2v  = (const float*)d_in[4];
    const float* hv   = (const float*)d_in[5];
    const float* stv  = (const float*)d_in[6];
    const float* txv  = (const float*)d_in[7];
    const float* tzv  = (const float*)d_in[8];
    const float* tLv  = (const float*)d_in[9];
    const float* w1f  = (const float*)d_in[10];
    const float* w2f  = (const float*)d_in[11];
    const float* w1b  = (const float*)d_in[12];
    const float* w2b  = (const float*)d_in[13];

    float* Zout  = (float*)d_out;                       // [9][NBP]
    float* Sout  = Zout + (size_t)NLAYERS * NBP;        // [9][NBP]
    float* WLout = Zout + 2 * (size_t)NLAYERS * NBP;    // [327*327]

    char* ws = (char*)d_ws;
    size_t off = 0;
    auto alloc = [&](size_t bytes) -> void* {
        void* p = ws + off;
        off += (bytes + 255) & ~(size_t)255;
        return p;
    };

    unsigned short* Wpk2f = (unsigned short*)alloc(72 * 64 * 8);
    unsigned short* Wpk1b = (unsigned short*)alloc(72 * 64 * 8);
    float* P    = (float*)alloc((size_t)NDIM * NDIM * 4);
    float* PB   = (float*)alloc((size_t)NBP * 4);
    float* Xa   = (float*)alloc((size_t)NBP * 4);
    float* Xb_  = (float*)alloc((size_t)NBP * 4);
    float* La   = (float*)alloc((size_t)NBP * 4);
    float* Lb_  = (float*)alloc((size_t)NBP * 4);
    float* zfb  = (float*)alloc((size_t)NBP * 4);   // doubles as hatx temp

    size_t rem = (ws_size > off + 4096) ? (ws_size - off - 4096) : 0;
    long long Ci = (long long)(rem / (2 * 25600 * 4));
    if (Ci > 2048) Ci = 2048;
    if (Ci < 1) Ci = 1;
    int C = (int)Ci;
    float* Abuf = (float*)alloc((size_t)C * 25600 * 4);
    float* Bbuf = (float*)alloc((size_t)C * 25600 * 4);

    int ew_grid = (NBP + 255) / 256;

    k_wpack<<<18, 256, 0, stream>>>(w2f, Wpk2f);
    k_wpack<<<18, 256, 0, stream>>>(w1b, Wpk1b);
    k_phitphi<<<dim3(50, 50), dim3(16, 16), 0, stream>>>(Wf, P);
    k_wloss<<<(MDIM * MDIM + 255) / 256, 256, 0, stream>>>(Wf, WLout);
    k_phitb<<<ew_grid, 256, 0, stream>>>(y, Wf, PB);

    float* Xcur = Xa; float* Xoth = Xb_;
    float* Lcur = La; float* Loth = Lb_;

    for (int i = 0; i < NLAYERS; ++i) {
        int mode = (i == 0) ? 0 : ((i == 1) ? 1 : 2);
        float* Zw = Zout + (size_t)i * NBP;
        const float* Zc = Zout + (size_t)((i >= 1) ? (i - 1) : 0) * NBP;
        const float* Zp = Zout + (size_t)((i >= 2) ? (i - 2) : 0) * NBP;

        float* Xn;
        if (i == 0) {
            Xn = Xcur;
            k_x0<<<ew_grid, 256, 0, stream>>>(PB, Xn, hv);
        } else {
            k_hatx<<<ew_grid, 256, 0, stream>>>(Xcur, Xoth, zfb, txv, i, mode);
            Xn = Xoth;
            k_xmm<<<dim3(13, 64), 256, 0, stream>>>(zfb, P, PB, Lcur, Zc, Xn,
                                                    hv, b1v, i, mode);
            float* t = Xcur; Xcur = Xn; Xoth = t;
        }

        k_zflat<<<ew_grid, 256, 0, stream>>>(Xn, Zc, Zp, Lcur, zfb, hv, b2v, tzv, i, mode);

        for (int c0 = 0; c0 < NB; c0 += C) {
            int g = (NB - c0 < C) ? (NB - c0) : C;
            k_conv1f<<<g, 512, 0, stream>>>(zfb, Abuf, w1f, c0);
            k_conv32m<<<g * 3, 512, 0, stream>>>(Abuf, Bbuf, Wpk2f, stv, i, 0, 0); // x_fwd
            k_conv32m<<<g * 3, 512, 0, stream>>>(Bbuf, Abuf, Wpk1b, stv, i, 1, 1); // relu(c1b(soft(x_fwd)))
            k_conv2b<<<g, 512, 0, stream>>>(Abuf, w2b, zfb, Zw, 0, c0);            // Zs[i]
            k_conv32m<<<g * 3, 512, 0, stream>>>(Bbuf, Abuf, Wpk1b, stv, i, 0, 1); // relu(c1b(x_fwd))
            k_conv2b<<<g, 512, 0, stream>>>(Abuf, w2b, zfb, Sout + (size_t)i * NBP, 1, c0); // syms[i]
        }

        k_lup<<<ew_grid, 256, 0, stream>>>(Xn, Zw, Lcur, Loth, Loth, hv, b1v, tLv, i, mode);
        { float* t = Lcur; Lcur = Loth; Loth = t; }
    }
}